// Round 4
// baseline (838.960 us; speedup 1.0000x reference)
//
#include <hip/hip_runtime.h>

#define BETA 0.96f
#define NB 4096
#define NI 96
#define NH 50
#define NO 2
#define NT 250
#define W1N (NI * NH)        // 4800
#define W1PAD (W1N + 64)     // tail pad so lane-loads never run OOB

// One-time transpose+flatten: w1flat[i*NH + h] = W1[h][i], zero-padded tail.
__global__ void w1_transpose_kernel(const float* __restrict__ W1,
                                    float* __restrict__ w1flat) {
    int idx = blockIdx.x * blockDim.x + threadIdx.x;
    if (idx >= W1PAD) return;
    float v = 0.0f;
    if (idx < W1N) {
        int i = idx / NH;
        int h = idx - i * NH;
        v = W1[h * NI + i];
    }
    w1flat[idx] = v;
}

// readlane with compile-time lane index: W1 broadcast without scalar memory.
// (v_readlane writes an SGPR; 1 SGPR operand per VALU fma is architecturally free.)
#define RL_FMA(WV, XV)                                                  \
    do {                                                                \
        _Pragma("unroll")                                               \
        for (int h_ = 0; h_ < NH; ++h_) {                               \
            float w_;                                                   \
            asm("v_readlane_b32 %0, %1, %2"                             \
                : "=s"(w_) : "v"(WV), "i"(h_));                         \
            acc[h_] = fmaf(XV, w_, acc[h_]);                            \
        }                                                               \
    } while (0)

// wave = one batch element b.
// Phase A (lanes = t): cur1 GEMM; x per-lane coalesced; W1 slice (50 floats)
//   lives in ONE VGPR's lanes, broadcast via v_readlane (no s_load stream).
// Phase B (lanes = h): serial LIF via LDS bounce; ballot -> spike masks.
// Phase C (lanes = t): mask-dot W2 + Kogge-Stone beta-weighted scan.
__global__ __launch_bounds__(64, 3) void snn_fused_kernel(
    const float* __restrict__ x,
    const float* __restrict__ w1flat,
    const float* __restrict__ W2,
    float* __restrict__ out)
{
    __shared__ float cur1_lds[NH][65];   // [h][t], +1 pad -> <=2-way banks
    const int b = blockIdx.x;
    const int lane = threadIdx.x;

    float mem1 = 0.0f;                   // lane = h role, persists across chunks
    float m2a = 0.0f, m2b = 0.0f;        // mem2 carry (wave-uniform)
    const float bpow = exp2f((float)(lane + 1) * -0.05889368905356867f); // beta^(lane+1)
    const int hcl = (lane < NH) ? lane : (NH - 1);

    const float* xrow_base = x + (size_t)b * (NI * NT);

    #pragma unroll 1
    for (int c = 0; c < 4; ++c) {
        const int t0 = c * 64;
        const int TT = (NT - t0 < 64) ? (NT - t0) : 64;           // 64,64,64,58
        const int tl = (t0 + lane < NT) ? (t0 + lane) : (NT - 1); // clamped t
        const float* xb = xrow_base + tl;

        // ---------------- Phase A: cur1[h] for my t, lanes = t ----------------
        float acc[NH];
        #pragma unroll
        for (int h = 0; h < NH; ++h) acc[h] = 0.0f;

        float xa[8], xc[8];
        #pragma unroll
        for (int g = 0; g < 8; ++g) xa[g] = xb[g * NT];   // i = 0..7
        float wva = w1flat[lane];                          // slice i = 0
        float wvb = 0.0f;

        for (int blk = 0; blk < 12; blk += 2) {            // rolled: small I$
            const int ib0 = blk * 8;
            // ---- sub-block A: consume xa (i = ib0+g), prefetch xc (blk+1) ----
            #pragma unroll
            for (int g = 0; g < 8; ++g) {
                int gin = ib0 + g + 1; if (gin > NI - 1) gin = NI - 1;
                if ((g & 1) == 0) {
                    wvb = w1flat[gin * NH + lane];
                    xc[g] = xb[(ib0 + 8 + g) * NT];
                    RL_FMA(wva, xa[g]);
                } else {
                    wva = w1flat[gin * NH + lane];
                    xc[g] = xb[(ib0 + 8 + g) * NT];
                    RL_FMA(wvb, xa[g]);
                }
            }
            // ---- sub-block B: consume xc (i = ib0+8+g), prefetch xa (blk+2) ----
            #pragma unroll
            for (int g = 0; g < 8; ++g) {
                int gin = ib0 + 9 + g; if (gin > NI - 1) gin = NI - 1;
                int inx = ib0 + 16 + g; if (inx > NI - 1) inx = NI - 1;
                if ((g & 1) == 0) {
                    wvb = w1flat[gin * NH + lane];
                    xa[g] = xb[inx * NT];
                    RL_FMA(wva, xc[g]);
                } else {
                    wva = w1flat[gin * NH + lane];
                    xa[g] = xb[inx * NT];
                    RL_FMA(wvb, xc[g]);
                }
            }
        }

        // ---------------- bounce cur1 to LDS: [h][t] ----------------
        #pragma unroll
        for (int h = 0; h < NH; ++h) cur1_lds[h][lane] = acc[h];

        // ---------------- Phase B: serial LIF, lanes = h ----------------
        unsigned vml = 0u, vmh = 0u;   // spike masks redistributed to lane = t
        for (int t = 0; t < TT; ++t) {
            const float cur = cur1_lds[hcl][t];
            const float base = fmaf(BETA, mem1, cur);
            mem1 = (mem1 > 1.0f) ? 0.0f : base;     // reset='zero'
            const unsigned long long m = __ballot(mem1 > 1.0f);
            const unsigned lo = (unsigned)(m & 0xffffffffull);
            const unsigned hi = (unsigned)(m >> 32);
            const bool mine = (lane == t);
            vml = mine ? lo : vml;
            vmh = mine ? hi : vmh;
        }

        // ---------------- Phase C: cur2 + mem2 scan, lanes = t ----------------
        float c2a = 0.0f, c2b = 0.0f;
        #pragma unroll
        for (int h = 0; h < NH; ++h) {
            const unsigned w = (h < 32) ? vml : vmh;
            const float bit = (float)((w >> (h & 31)) & 1u);
            c2a = fmaf(bit, W2[h], c2a);          // W2[0][h]
            c2b = fmaf(bit, W2[NH + h], c2b);     // W2[1][h]
        }
        float sa = c2a, sb = c2b;
        float bk = BETA;
        #pragma unroll
        for (int k = 1; k <= 32; k <<= 1) {
            const float pa = __shfl_up(sa, (unsigned)k, 64);
            const float pb = __shfl_up(sb, (unsigned)k, 64);
            if (lane >= k) {
                sa = fmaf(bk, pa, sa);
                sb = fmaf(bk, pb, sb);
            }
            bk *= bk;
        }
        const float outa = fmaf(bpow, m2a, sa);   // + beta^(lane+1) * carry
        const float outb = fmaf(bpow, m2b, sb);
        m2a = __shfl(outa, TT - 1, 64);
        m2b = __shfl(outb, TT - 1, 64);
        if (lane < TT) {
            out[((size_t)b * NO + 0) * NT + t0 + lane] = outa;
            out[((size_t)b * NO + 1) * NT + t0 + lane] = outb;
        }
    }
}

extern "C" void kernel_launch(void* const* d_in, const int* in_sizes, int n_in,
                              void* d_out, int out_size, void* d_ws, size_t ws_size,
                              hipStream_t stream) {
    const float* x  = (const float*)d_in[0];
    const float* W1 = (const float*)d_in[1];
    const float* W2 = (const float*)d_in[2];
    float* out = (float*)d_out;
    float* w1flat = (float*)d_ws;   // W1PAD floats = 19.5 KB scratch

    hipLaunchKernelGGL(w1_transpose_kernel, dim3((W1PAD + 255) / 256),
                       dim3(256), 0, stream, W1, w1flat);
    hipLaunchKernelGGL(snn_fused_kernel, dim3(NB), dim3(64), 0, stream,
                       x, w1flat, W2, out);
}

// Round 5
// 687.460 us; speedup vs baseline: 1.2204x; 1.2204x over previous
//
#include <hip/hip_runtime.h>

#define BETA 0.96f
#define NB 4096
#define NI 96
#define NH 50
#define NO 2
#define NT 250
#define WST 52                 // padded W1 row: 52 floats = 208 B (16B-aligned)
#define W1SZ (NI * WST)        // 4992 floats

// One-time transpose+pad: w1pad[i*WST + h] = W1[h][i], zeros in pad lanes.
__global__ void w1_transpose_kernel(const float* __restrict__ W1,
                                    float* __restrict__ w1pad) {
    int idx = blockIdx.x * blockDim.x + threadIdx.x;
    if (idx >= W1SZ) return;
    int i = idx / WST;
    int h = idx - i * WST;
    w1pad[idx] = (h < NH) ? W1[h * NI + i] : 0.0f;
}

// Block = 4 waves = 4 batch elements. W1 staged once into LDS per block;
// inner loop = uniform-address ds_read_b128 (broadcast, LDS pipe) + v_fmac
// (1 VALU instr per MAC). No scalar memory, no readlane in the hot loop.
// Phase A (lanes = t): cur1 GEMM, x per-lane coalesced.
// Phase B (lanes = h): serial LIF via per-wave LDS bounce; ballot -> masks.
// Phase C (lanes = t): mask-dot W2 + Kogge-Stone beta-weighted scan.
__global__ __launch_bounds__(256, 2) void snn_fused_kernel(
    const float* __restrict__ x,
    const float* __restrict__ w1pad,
    const float* __restrict__ W2,
    float* __restrict__ out)
{
    __shared__ float w1s[W1SZ];            // 19968 B
    __shared__ float cur1[4][NH][65];      // 4 x 13000 B, [h][t], pad -> 2-way
    const int wid  = threadIdx.x >> 6;
    const int lane = threadIdx.x & 63;
    const int b = (blockIdx.x << 2) + wid;

    // ---- stage W1 (once per block) ----
    for (int idx = threadIdx.x; idx < W1SZ; idx += 256)
        w1s[idx] = w1pad[idx];
    __syncthreads();

    float mem1 = 0.0f;                     // lane = h state, persists over chunks
    float m2a = 0.0f, m2b = 0.0f;          // mem2 carry
    const float bpow = exp2f((float)(lane + 1) * -0.05889368905356867f); // beta^(lane+1)
    const int hcl = (lane < NH) ? lane : (NH - 1);

    const float* xrow_base = x + (size_t)b * (NI * NT);

    #pragma unroll 1
    for (int c = 0; c < 4; ++c) {
        const int t0 = c * 64;
        const int TT = (NT - t0 < 64) ? (NT - t0) : 64;           // 64,64,64,58
        const int tl = (t0 + lane < NT) ? (t0 + lane) : (NT - 1); // clamped t
        const float* xb = xrow_base + tl;

        // ---------------- Phase A: cur1[h] for my t, lanes = t ----------------
        float acc[WST];
        #pragma unroll
        for (int h = 0; h < WST; ++h) acc[h] = 0.0f;

        float xa[8], xc[8];
        #pragma unroll
        for (int g = 0; g < 8; ++g) xa[g] = xb[g * NT];   // i = 0..7

        #pragma unroll 1
        for (int blk = 0; blk < 12; blk += 2) {
            const int ib0 = blk * 8;
            // prefetch x for blk+1
            #pragma unroll
            for (int g = 0; g < 8; ++g) xc[g] = xb[(ib0 + 8 + g) * NT];
            // consume blk
            #pragma unroll
            for (int g = 0; g < 8; ++g) {
                const float4* wr = (const float4*)&w1s[(ib0 + g) * WST];
                const float xv = xa[g];
                #pragma unroll
                for (int k = 0; k < 13; ++k) {
                    const float4 w = wr[k];          // ds_read_b128, broadcast
                    acc[4*k+0] = fmaf(xv, w.x, acc[4*k+0]);
                    acc[4*k+1] = fmaf(xv, w.y, acc[4*k+1]);
                    acc[4*k+2] = fmaf(xv, w.z, acc[4*k+2]);
                    acc[4*k+3] = fmaf(xv, w.w, acc[4*k+3]);
                }
            }
            // prefetch x for blk+2 (clamped; tail loads are dummies)
            #pragma unroll
            for (int g = 0; g < 8; ++g) {
                int inx = ib0 + 16 + g; if (inx > NI - 1) inx = NI - 1;
                xa[g] = xb[inx * NT];
            }
            // consume blk+1
            #pragma unroll
            for (int g = 0; g < 8; ++g) {
                const float4* wr = (const float4*)&w1s[(ib0 + 8 + g) * WST];
                const float xv = xc[g];
                #pragma unroll
                for (int k = 0; k < 13; ++k) {
                    const float4 w = wr[k];
                    acc[4*k+0] = fmaf(xv, w.x, acc[4*k+0]);
                    acc[4*k+1] = fmaf(xv, w.y, acc[4*k+1]);
                    acc[4*k+2] = fmaf(xv, w.z, acc[4*k+2]);
                    acc[4*k+3] = fmaf(xv, w.w, acc[4*k+3]);
                }
            }
        }

        // ---------------- bounce cur1 to LDS: [h][t] (per-wave buffer) -------
        #pragma unroll
        for (int h = 0; h < NH; ++h) cur1[wid][h][lane] = acc[h];

        // ---------------- Phase B: serial LIF, lanes = h ----------------
        unsigned vml = 0u, vmh = 0u;       // spike masks redistributed to lane=t
        for (int t = 0; t < TT; ++t) {
            const float cur = cur1[wid][hcl][t];
            const float base = fmaf(BETA, mem1, cur);
            mem1 = (mem1 > 1.0f) ? 0.0f : base;      // reset='zero'
            const unsigned long long m = __ballot(mem1 > 1.0f);
            const unsigned lo = (unsigned)(m & 0xffffffffull);
            const unsigned hi = (unsigned)(m >> 32);
            const bool mine = (lane == t);
            vml = mine ? lo : vml;
            vmh = mine ? hi : vmh;
        }

        // ---------------- Phase C: cur2 + mem2 scan, lanes = t ----------------
        float c2a = 0.0f, c2b = 0.0f;
        #pragma unroll
        for (int h = 0; h < NH; ++h) {
            const unsigned w = (h < 32) ? vml : vmh;
            const float bit = (float)((w >> (h & 31)) & 1u);
            c2a = fmaf(bit, W2[h], c2a);             // W2[0][h]
            c2b = fmaf(bit, W2[NH + h], c2b);        // W2[1][h]
        }
        float sa = c2a, sb = c2b;
        float bk = BETA;
        #pragma unroll
        for (int k = 1; k <= 32; k <<= 1) {
            const float pa = __shfl_up(sa, (unsigned)k, 64);
            const float pb = __shfl_up(sb, (unsigned)k, 64);
            if (lane >= k) {
                sa = fmaf(bk, pa, sa);
                sb = fmaf(bk, pb, sb);
            }
            bk *= bk;
        }
        const float outa = fmaf(bpow, m2a, sa);      // + beta^(lane+1) * carry
        const float outb = fmaf(bpow, m2b, sb);
        m2a = __shfl(outa, TT - 1, 64);
        m2b = __shfl(outb, TT - 1, 64);
        if (lane < TT) {
            out[((size_t)b * NO + 0) * NT + t0 + lane] = outa;
            out[((size_t)b * NO + 1) * NT + t0 + lane] = outb;
        }
    }
}

extern "C" void kernel_launch(void* const* d_in, const int* in_sizes, int n_in,
                              void* d_out, int out_size, void* d_ws, size_t ws_size,
                              hipStream_t stream) {
    const float* x  = (const float*)d_in[0];
    const float* W1 = (const float*)d_in[1];
    const float* W2 = (const float*)d_in[2];
    float* out = (float*)d_out;
    float* w1pad = (float*)d_ws;   // W1SZ floats = 19.97 KB scratch

    hipLaunchKernelGGL(w1_transpose_kernel, dim3((W1SZ + 255) / 256),
                       dim3(256), 0, stream, W1, w1pad);
    hipLaunchKernelGGL(snn_fused_kernel, dim3(NB / 4), dim3(256), 0, stream,
                       x, w1pad, W2, out);
}